// Round 3
// baseline (468.689 us; speedup 1.0000x reference)
//
#include <hip/hip_runtime.h>
#include <hip/hip_cooperative_groups.h>
#include <stdint.h>

namespace cg = cooperative_groups;

#define NB 2
#define NN 100
#define HWP (800*1344)            // 1,075,200 pixels per image
#define GCH 10                    // instances per chunk
#define NCHMAX ((NN + GCH - 1)/GCH)   // 10
#define NKEY (1<<(GCH+1))         // 2048 bins: claimed bit + 10 membership bits
#define NSEM 134
#define IGN 133
#define THR 256
#define GRID 256                  // 1 block/CU -> cooperative co-residency GUARANTEED
#define BPI (GRID/NB)             // 128 blocks per image
#define PPB (HWP/BPI)             // 8400 pixels per block (8400 = 525*16)
#define GRAN (PPB/16)             // 525 granules of 16 px
#define NSWEEP ((GRAN + THR - 1)/THR) // 3

struct WS {
  unsigned hist[NCHMAX][NB][NKEY];   // zeroed stripe (with counts)
  unsigned counts[NB][NSEM];
  int      order[NB][NN];
  float    score_s[NB][NN];
  int      cls_s[NB][NN];
  unsigned Mcnt[NB];
  unsigned flag;                     // 1 = u8 bools, 0 = int32
};
#define ZW (NCHMAX*NB*NKEY + NB*NSEM)   // 41,228 words <= 65,536 threads

__device__ __forceinline__ unsigned load_bits16(const void* __restrict__ masks,
                                                size_t base, int mode_u8) {
  if (mode_u8) {
    uint4 v = *(const uint4*)((const uint8_t*)masks + base);
    unsigned n0 = (((v.x & 0x01010101u) * 0x01020408u) >> 24) & 0xFu;
    unsigned n1 = (((v.y & 0x01010101u) * 0x01020408u) >> 24) & 0xFu;
    unsigned n2 = (((v.z & 0x01010101u) * 0x01020408u) >> 24) & 0xFu;
    unsigned n3 = (((v.w & 0x01010101u) * 0x01020408u) >> 24) & 0xFu;
    return n0 | (n1 << 4) | (n2 << 8) | (n3 << 12);
  } else {
    const uint4* mp = (const uint4*)((const int*)masks + base);
    unsigned bits = 0;
    #pragma unroll
    for (int q = 0; q < 4; ++q) {
      uint4 v = mp[q];
      bits |= ((v.x & 1u) | ((v.y & 1u) << 1) | ((v.z & 1u) << 2) |
               ((v.w & 1u) << 3)) << (q * 4);
    }
    return bits;
  }
}

__global__ __launch_bounds__(THR) void fused_panfuse_kernel(
    const void* __restrict__ masks, const float* __restrict__ scores,
    const int* __restrict__ cls, const int* __restrict__ sem,
    int* __restrict__ out, WS* __restrict__ ws) {
  cg::grid_group grid = cg::this_grid();

  __shared__ __align__(16) uint8_t  owner[PPB];   // 0xFF = free, else rank 0..99
  __shared__ uint16_t memb[PPB];                  // per-chunk key (claimed+memb bits)
  __shared__ uint8_t  semu8[PPB];
  __shared__ unsigned lh[NKEY];                   // hist / sort scratch / sval
  __shared__ int      pval[NN];
  __shared__ uint8_t  iidArr[NN];
  __shared__ int      midx[GCH];
  __shared__ unsigned sh_kmask, sh_kc, shDet;

  const int t   = threadIdx.x;
  const int gid = blockIdx.x;
  const int b   = gid / BPI;
  const int bx  = gid % BPI;
  const size_t pbase = (size_t)b * HWP + (size_t)bx * PPB;  // global pixel base

  // ---------------- phase 0 ----------------
  {
    unsigned tg = (unsigned)gid * THR + t;
    if (tg < (unsigned)ZW) (&ws->hist[0][0][0])[tg] = 0;
  }
  for (int i = t; i < PPB; i += THR) owner[i] = 0xFF;
  for (int i = t; i < NN; i += THR) iidArr[i] = 0;
  if (t == 0) { sh_kc = 0; shDet = 0; }

  if (gid == 0) {
    const unsigned* mw = (const unsigned*)masks;
    unsigned any = 0;
    for (int i = t; i < 4096; i += THR) any |= (mw[i] > 1u) ? 1u : 0u;
    float* ss = (float*)lh;                  // 200 floats fit
    for (int i = t; i < NB * NN; i += THR) ss[i] = scores[i];
    if (t < NB) ws->Mcnt[t] = 0;
    __syncthreads();
    if (any) atomicOr(&shDet, 1u);
    __syncthreads();
    if (t == 0) ws->flag = shDet;
    // stable descending rank of candidates (score >= 0.5); others are no-ops
    for (int idx = t; idx < NB * NN; idx += THR) {
      int bb = idx / NN, i = idx % NN;
      float s = ss[bb * NN + i];
      if (s >= 0.5f) {
        int r = 0;
        for (int j = 0; j < NN; ++j) {
          float sj = ss[bb * NN + j];
          if (sj >= 0.5f && (sj > s || (sj == s && j < i))) r++;
        }
        ws->order[bb][r]   = i;
        ws->score_s[bb][r] = s;
        ws->cls_s[bb][r]   = cls[bb * NN + i];
        atomicAdd(&ws->Mcnt[bb], 1u);
      }
    }
  }
  __threadfence();
  grid.sync();

  const int mode_u8 = (int)ws->flag;
  const int M  = (int)ws->Mcnt[b];
  const int M0 = (int)ws->Mcnt[0];
  const int M1 = (int)ws->Mcnt[1];
  const int maxM = M0 > M1 ? M0 : M1;
  const int nch = (maxM + GCH - 1) / GCH;   // grid-uniform trip count

  // ---------------- main chunk loop: 1 grid.sync per chunk ----------------
  for (int c = 0; c < nch; ++c) {
    int L = M - c * GCH; if (L > GCH) L = GCH;   // block-uniform (may be <=0)
    for (int i = t; i < NKEY; i += THR) lh[i] = 0;
    if (t < GCH) midx[t] = (t < L) ? ws->order[b][c * GCH + t] : 0;
    __syncthreads();

    if (L > 0) {
      for (int s = 0; s < NSWEEP; ++s) {
        int gr = s * THR + t;
        if (gr < GRAN) {
          int l0 = gr * 16;
          uint4 ov = *(const uint4*)(owner + l0);
          unsigned w_[4] = {ov.x, ov.y, ov.z, ov.w};
          unsigned key[16];
          #pragma unroll
          for (int k = 0; k < 16; ++k) {
            unsigned by = (w_[k >> 2] >> ((k & 3) * 8)) & 0xFFu;
            key[k] = (by != 0xFFu) ? (1u << GCH) : 0u;
          }
          for (int g = 0; g < L; ++g) {
            size_t base = ((size_t)(b * NN + midx[g])) * HWP + (size_t)bx * PPB + l0;
            unsigned bits16 = load_bits16(masks, base, mode_u8);
            #pragma unroll
            for (int k = 0; k < 16; ++k) key[k] |= ((bits16 >> k) & 1u) << g;
          }
          #pragma unroll
          for (int k = 0; k < 16; ++k) {
            memb[l0 + k] = (uint16_t)key[k];
            atomicAdd(&lh[key[k]], 1u);
          }
        }
      }
    }
    __syncthreads();
    if (L > 0) {
      for (int i = t; i < NKEY; i += THR) {
        unsigned v = lh[i];
        if (v) atomicAdd(&ws->hist[c][b][i], v);
      }
    }
    grid.sync();

    // resolve redundantly per block (same inputs -> same decisions everywhere)
    if (L > 0) {
      for (int i = t; i < NKEY; i += THR) lh[i] = ws->hist[c][b][i];
      __syncthreads();
      if (t < 64) {
        unsigned kmask = 0;
        unsigned kc = sh_kc;
        for (int g = 0; g < L; ++g) {
          unsigned sel = kmask & ((1u << g) - 1u);
          unsigned area = 0, inter = 0;
          for (int i = t; i < NKEY; i += 64) {
            unsigned h = lh[i];
            if (h && (((unsigned)i >> g) & 1u)) {
              area += h;
              if (((unsigned)i >> GCH) | ((unsigned)i & sel)) inter += h;
            }
          }
          #pragma unroll
          for (int off = 32; off; off >>= 1) {
            area  += __shfl_xor(area, off);
            inter += __shfl_xor(inter, off);
          }
          float s = ws->score_s[b][c * GCH + g];
          // inter <= 0.5f*area (exact in f32, area < 2^24)  <=>  2*inter <= area
          bool keep = (s >= 0.5f) && (area > 0u) && (2u * inter <= area);
          if (keep) {
            kmask |= 1u << g;
            kc += 1;
            if (t == 0) iidArr[c * GCH + g] = (uint8_t)kc;
          }
        }
        if (t == 0) { sh_kmask = kmask; sh_kc = kc; }
      }
    } else if (t == 0) sh_kmask = 0;
    __syncthreads();

    unsigned km = sh_kmask;   // bits < GCH only, so claimed bit in memb is ignored
    if (km) {
      for (int s = 0; s < NSWEEP; ++s) {
        int gr = s * THR + t;
        if (gr < GRAN) {
          int l0 = gr * 16;
          #pragma unroll
          for (int k = 0; k < 16; ++k) {
            if (owner[l0 + k] == 0xFF) {
              unsigned hit = memb[l0 + k] & km;
              if (hit) owner[l0 + k] = (uint8_t)(c * GCH + __builtin_ctz(hit));
            }
          }
        }
      }
    }
    __syncthreads();
  }

  // ---------------- stuff area counts over unclaimed pixels ----------------
  for (int i = t; i < NSEM; i += THR) lh[i] = 0;
  __syncthreads();
  for (int s = 0; s < NSWEEP; ++s) {
    int gr = s * THR + t;
    if (gr < GRAN) {
      int l0 = gr * 16;
      const uint4* sp = (const uint4*)(sem + pbase + l0);
      uint4 ov = *(const uint4*)(owner + l0);
      unsigned w_[4] = {ov.x, ov.y, ov.z, ov.w};
      #pragma unroll
      for (int q = 0; q < 4; ++q) {
        uint4 sv = sp[q];
        unsigned sarr[4] = {sv.x, sv.y, sv.z, sv.w};
        #pragma unroll
        for (int j = 0; j < 4; ++j) {
          int k = q * 4 + j;
          semu8[l0 + k] = (uint8_t)sarr[j];
          unsigned by = (w_[k >> 2] >> ((k & 3) * 8)) & 0xFFu;
          if (by == 0xFFu && sarr[j] != (unsigned)IGN) atomicAdd(&lh[sarr[j]], 1u);
        }
      }
    }
  }
  __syncthreads();
  for (int i = t; i < NSEM; i += THR) {
    unsigned v = lh[i];
    if (v) atomicAdd(&ws->counts[b][i], v);
  }
  grid.sync();

  // ---------------- final pan write ----------------
  int* sval = (int*)lh;
  for (int i = t; i < NSEM; i += THR)
    sval[i] = (i != IGN && ws->counts[b][i] >= 4096u) ? (i + 80) : 0;
  for (int i = t; i < NN; i += THR)
    pval[i] = ws->cls_s[b][i] + (int)iidArr[i] * 1000;
  __syncthreads();
  for (int s = 0; s < NSWEEP; ++s) {
    int gr = s * THR + t;
    if (gr < GRAN) {
      int l0 = gr * 16;
      int4* op = (int4*)(out + pbase + l0);
      #pragma unroll
      for (int q = 0; q < 4; ++q) {
        int res[4];
        #pragma unroll
        for (int j = 0; j < 4; ++j) {
          int k = q * 4 + j;
          uint8_t r = owner[l0 + k];
          res[j] = (r != 0xFFu) ? pval[r] : sval[semu8[l0 + k]];
        }
        op[q] = make_int4(res[0], res[1], res[2], res[3]);
      }
    }
  }
}

extern "C" void kernel_launch(void* const* d_in, const int* in_sizes, int n_in,
                              void* d_out, int out_size, void* d_ws, size_t ws_size,
                              hipStream_t stream) {
  const void*  masks  = d_in[0];
  const float* scores = (const float*)d_in[1];
  const int*   cls    = (const int*)d_in[2];
  const int*   sem    = (const int*)d_in[3];
  int* out = (int*)d_out;
  WS*  ws  = (WS*)d_ws;

  void* args[] = { (void*)&masks, (void*)&scores, (void*)&cls,
                   (void*)&sem, (void*)&out, (void*)&ws };
  hipLaunchCooperativeKernel((void*)fused_panfuse_kernel,
                             dim3(GRID), dim3(THR), args, 0, stream);
}

// Round 4
// 453.097 us; speedup vs baseline: 1.0344x; 1.0344x over previous
//
#include <hip/hip_runtime.h>
#include <hip/hip_cooperative_groups.h>
#include <stdint.h>

namespace cg = cooperative_groups;

#define NB 2
#define NN 100
#define HWP (800*1344)            // 1,075,200 pixels per image
#define GCH 10                    // instances per chunk
#define NCHMAX ((NN + GCH - 1)/GCH)   // 10
#define NKEY (1<<(GCH+1))         // 2048 bins: claimed bit (0x400) + 10 membership bits
#define CBIT (1u<<GCH)
#define NSEM 134
#define IGN 133
#define THR 1024                  // 16 waves/block
#define GRID 256                  // 1 block/CU -> cooperative co-residency GUARANTEED
#define BPI (GRID/NB)             // 128 blocks per image
#define PPB (HWP/BPI)             // 8400 pixels per block
#define GPX 8                     // pixels per granule
#define NG (PPB/GPX)              // 1050 granules per block

struct WS {
  unsigned hist[NCHMAX][NB][NKEY];
  unsigned counts[NB][NSEM];
  int      order[NB][NN];
  float    score_s[NB][NN];
  int      cls_s[NB][NN];
  unsigned Mcnt[NB];
  unsigned flag;                   // 1 = u8 bools, 0 = int32
};
#define ZW (NCHMAX*NB*NKEY + NB*NSEM)

__device__ __forceinline__ unsigned u8x8_to_bits(uint2 v) {
  unsigned lo = (((v.x & 0x01010101u) * 0x01020408u) >> 24) & 0xFu;
  unsigned hi = (((v.y & 0x01010101u) * 0x01020408u) >> 24) & 0xFu;
  return lo | (hi << 4);
}

__global__ __launch_bounds__(THR, 4) void fused_panfuse_kernel(
    const void* __restrict__ masks, const float* __restrict__ scores,
    const int* __restrict__ cls, const int* __restrict__ sem,
    int* __restrict__ out, WS* __restrict__ ws) {
  cg::grid_group grid = cg::this_grid();

  __shared__ __align__(16) uint8_t  owner[PPB];   // 0xFF = free, else rank 0..99
  __shared__ __align__(16) uint16_t memb[PPB];    // per-chunk key bits per pixel
  __shared__ __align__(16) uint8_t  semu8[PPB];
  __shared__ unsigned lh[NKEY];                   // hist / sort scratch / sval
  __shared__ int      pval[NN];
  __shared__ uint8_t  iidArr[NN];
  __shared__ int      midx[GCH];
  __shared__ unsigned sh_kmask, sh_kc, shDet;

  const int t   = threadIdx.x;
  const int gid = blockIdx.x;
  const int b   = gid / BPI;
  const int bx  = gid % BPI;
  const size_t pbase = (size_t)b * HWP + (size_t)bx * PPB;

  // ---------------- phase 0 ----------------
  {
    unsigned tg = (unsigned)gid * THR + t;
    if (tg < (unsigned)ZW) (&ws->hist[0][0][0])[tg] = 0;
  }
  for (int i = t; i < PPB; i += THR) owner[i] = 0xFF;
  if (t < NN) iidArr[t] = 0;
  if (t == 0) { sh_kc = 0; shDet = 0; }

  if (gid == 0) {
    const unsigned* mw = (const unsigned*)masks;
    unsigned any = 0;
    for (int i = t; i < 4096; i += THR) any |= (mw[i] > 1u) ? 1u : 0u;
    float* ss = (float*)lh;                 // 200 floats fit in lh
    if (t < NB * NN) ss[t] = scores[t];
    if (t < NB) ws->Mcnt[t] = 0;
    __syncthreads();
    if (any) atomicOr(&shDet, 1u);
    __syncthreads();
    if (t == 0) ws->flag = shDet;
    if (t < NB * NN) {
      int bb = t / NN, i = t % NN;
      float s = ss[bb * NN + i];
      if (s >= 0.5f) {   // only candidates can ever be kept; others are no-ops
        int r = 0;
        for (int j = 0; j < NN; ++j) {
          float sj = ss[bb * NN + j];
          if (sj >= 0.5f && (sj > s || (sj == s && j < i))) r++;
        }
        ws->order[bb][r]   = i;
        ws->score_s[bb][r] = s;
        ws->cls_s[bb][r]   = cls[bb * NN + i];
        atomicAdd(&ws->Mcnt[bb], 1u);
      }
    }
  }
  __threadfence();
  grid.sync();

  const int mode_u8 = (int)ws->flag;
  const int M  = (int)ws->Mcnt[b];
  const int M0 = (int)ws->Mcnt[0];
  const int M1 = (int)ws->Mcnt[1];
  const int maxM = M0 > M1 ? M0 : M1;
  const int nch = (maxM + GCH - 1) / GCH;   // grid-uniform trip count

  // ---------------- main chunk loop: 1 grid.sync per chunk ----------------
  for (int c = 0; c < nch; ++c) {
    int L = M - c * GCH; if (L > GCH) L = GCH;   // block-uniform (may be <=0)
    for (int i = t; i < NKEY; i += THR) lh[i] = 0;
    if (t < GCH) midx[t] = ws->order[b][(t < L) ? (c * GCH + t) : (c * GCH)];
    __syncthreads();

    if (L > 0) {
      const unsigned lm = (L >= GCH) ? (CBIT - 1u) : ((1u << L) - 1u);
      int midx_r[GCH];
      #pragma unroll
      for (int g = 0; g < GCH; ++g)
        midx_r[g] = __builtin_amdgcn_readfirstlane(midx[g]);

      for (int s = 0; s < 2; ++s) {
        int gr = s * THR + t;
        if (gr < NG) {
          int l0 = gr * GPX;
          uint2 ov = *(const uint2*)(owner + l0);
          unsigned key[GPX];
          #pragma unroll
          for (int k = 0; k < GPX; ++k) {
            unsigned by = ((k < 4 ? ov.x : ov.y) >> ((k & 3) * 8)) & 0xFFu;
            key[k] = (by != 0xFFu) ? CBIT : 0u;
          }
          if (mode_u8) {
            #pragma unroll
            for (int g = 0; g < GCH; ++g) {
              const uint8_t* mp = (const uint8_t*)masks +
                  (size_t)(b * NN + midx_r[g]) * HWP + (size_t)bx * PPB + l0;
              unsigned b8 = u8x8_to_bits(*(const uint2*)mp);
              #pragma unroll
              for (int k = 0; k < GPX; ++k) key[k] |= ((b8 >> k) & 1u) << g;
            }
          } else {
            #pragma unroll 2
            for (int g = 0; g < GCH; ++g) {
              const uint4* mp = (const uint4*)((const int*)masks +
                  (size_t)(b * NN + midx_r[g]) * HWP + (size_t)bx * PPB + l0);
              uint4 a = mp[0], bq = mp[1];
              unsigned b8 = (a.x & 1u) | ((a.y & 1u) << 1) | ((a.z & 1u) << 2) |
                            ((a.w & 1u) << 3) | ((bq.x & 1u) << 4) |
                            ((bq.y & 1u) << 5) | ((bq.z & 1u) << 6) |
                            ((bq.w & 1u) << 7);
              #pragma unroll
              for (int k = 0; k < GPX; ++k) key[k] |= ((b8 >> k) & 1u) << g;
            }
          }
          unsigned fk[GPX];
          #pragma unroll
          for (int k = 0; k < GPX; ++k)
            fk[k] = (key[k] & lm) | (key[k] & CBIT);
          uint4 pk;
          pk.x = fk[0] | (fk[1] << 16); pk.y = fk[2] | (fk[3] << 16);
          pk.z = fk[4] | (fk[5] << 16); pk.w = fk[6] | (fk[7] << 16);
          *(uint4*)(memb + l0) = pk;
          #pragma unroll
          for (int k = 0; k < GPX; ++k) atomicAdd(&lh[fk[k]], 1u);
        }
      }
    }
    __syncthreads();
    if (L > 0) {
      for (int i = t; i < NKEY; i += THR) {
        unsigned v = lh[i];
        if (v) atomicAdd(&ws->hist[c][b][i], v);
      }
    }
    grid.sync();

    // resolve redundantly per block (same inputs -> same decisions everywhere)
    if (L > 0) {
      for (int i = t; i < NKEY; i += THR) lh[i] = ws->hist[c][b][i];
      __syncthreads();
      if (t < 64) {
        unsigned kmask = 0;
        unsigned kc = sh_kc;
        for (int g = 0; g < L; ++g) {
          unsigned sel = kmask & ((1u << g) - 1u);
          unsigned area = 0, inter = 0;
          for (int i = t; i < NKEY; i += 64) {
            unsigned h = lh[i];
            if (h && (((unsigned)i >> g) & 1u)) {
              area += h;
              if (((unsigned)i >> GCH) | ((unsigned)i & sel)) inter += h;
            }
          }
          #pragma unroll
          for (int off = 32; off; off >>= 1) {
            area  += __shfl_xor(area, off);
            inter += __shfl_xor(inter, off);
          }
          float s = ws->score_s[b][c * GCH + g];
          // inter <= 0.5f*area (exact in f32, area < 2^24)  <=>  2*inter <= area
          bool keep = (s >= 0.5f) && (area > 0u) && (2u * inter <= area);
          if (keep) {
            kmask |= 1u << g;
            kc += 1;
            if (t == 0) iidArr[c * GCH + g] = (uint8_t)kc;
          }
        }
        if (t == 0) { sh_kmask = kmask; sh_kc = kc; }
      }
    } else if (t == 0) sh_kmask = 0;
    __syncthreads();

    unsigned km = sh_kmask;   // bits < GCH, so the claimed bit in memb never matches
    if (km) {
      for (int s = 0; s < 2; ++s) {
        int gr = s * THR + t;
        if (gr < NG) {
          int l0 = gr * GPX;
          #pragma unroll
          for (int k = 0; k < GPX; ++k) {
            if (owner[l0 + k] == 0xFF) {
              unsigned hit = memb[l0 + k] & km;
              if (hit) owner[l0 + k] = (uint8_t)(c * GCH + __builtin_ctz(hit));
            }
          }
        }
      }
    }
    __syncthreads();
  }

  // ---------------- stuff area counts over unclaimed pixels ----------------
  for (int i = t; i < NSEM; i += THR) lh[i] = 0;
  __syncthreads();
  for (int s = 0; s < 2; ++s) {
    int gr = s * THR + t;
    if (gr < NG) {
      int l0 = gr * GPX;
      const uint4* sp = (const uint4*)(sem + pbase + l0);
      uint4 sv0 = sp[0], sv1 = sp[1];
      uint2 ov = *(const uint2*)(owner + l0);
      unsigned sarr[8] = {sv0.x, sv0.y, sv0.z, sv0.w, sv1.x, sv1.y, sv1.z, sv1.w};
      #pragma unroll
      for (int k = 0; k < GPX; ++k) {
        semu8[l0 + k] = (uint8_t)sarr[k];
        unsigned by = ((k < 4 ? ov.x : ov.y) >> ((k & 3) * 8)) & 0xFFu;
        if (by == 0xFFu && sarr[k] != (unsigned)IGN) atomicAdd(&lh[sarr[k]], 1u);
      }
    }
  }
  __syncthreads();
  for (int i = t; i < NSEM; i += THR) {
    unsigned v = lh[i];
    if (v) atomicAdd(&ws->counts[b][i], v);
  }
  grid.sync();

  // ---------------- final pan write ----------------
  int* sval = (int*)lh;
  for (int i = t; i < NSEM; i += THR)
    sval[i] = (i != IGN && ws->counts[b][i] >= 4096u) ? (i + 80) : 0;
  if (t < NN) pval[t] = ws->cls_s[b][t] + (int)iidArr[t] * 1000;
  __syncthreads();
  for (int s = 0; s < 2; ++s) {
    int gr = s * THR + t;
    if (gr < NG) {
      int l0 = gr * GPX;
      int4* op = (int4*)(out + pbase + l0);
      #pragma unroll
      for (int q = 0; q < 2; ++q) {
        int res[4];
        #pragma unroll
        for (int j = 0; j < 4; ++j) {
          int k = q * 4 + j;
          uint8_t r = owner[l0 + k];
          res[j] = (r != 0xFFu) ? pval[r] : sval[semu8[l0 + k]];
        }
        op[q] = make_int4(res[0], res[1], res[2], res[3]);
      }
    }
  }
}

extern "C" void kernel_launch(void* const* d_in, const int* in_sizes, int n_in,
                              void* d_out, int out_size, void* d_ws, size_t ws_size,
                              hipStream_t stream) {
  const void*  masks  = d_in[0];
  const float* scores = (const float*)d_in[1];
  const int*   cls    = (const int*)d_in[2];
  const int*   sem    = (const int*)d_in[3];
  int* out = (int*)d_out;
  WS*  ws  = (WS*)d_ws;

  void* args[] = { (void*)&masks, (void*)&scores, (void*)&cls,
                   (void*)&sem, (void*)&out, (void*)&ws };
  hipLaunchCooperativeKernel((void*)fused_panfuse_kernel,
                             dim3(GRID), dim3(THR), args, 0, stream);
}

// Round 5
// 188.529 us; speedup vs baseline: 2.4860x; 2.4033x over previous
//
#include <hip/hip_runtime.h>
#include <stdint.h>

#define NB 2
#define NN 100
#define HWP (800*1344)            // 1,075,200 pixels per image
#define GCH 10                    // instances per chunk
#define NCHMAX 10
#define NKEY (1<<(GCH+1))         // 2048 bins: claimed bit (0x400) + 10 membership bits
#define CBIT (1u<<GCH)
#define NSEM 134
#define IGN 133
#define THR 1024
#define BPI 128                   // blocks per image
#define GRID (NB*BPI)             // 256
#define PPB (HWP/BPI)             // 8400 pixels per block
#define GPX 8
#define NG (PPB/GPX)              // 1050 granules per block

struct WS {
  unsigned hist[NCHMAX][NB][NKEY];   // |-- zeroed stripe start
  unsigned counts[NB][NSEM];
  int      iid[NB][NN];              // |-- zeroed stripe end
  int      order[NB][NN];
  float    score_s[NB][NN];
  int      cls_s[NB][NN];
  unsigned kcAfter[NCHMAX][NB];
  unsigned Mcnt[NB];
  unsigned flag;                     // 1 = u8 bools, 0 = int32
};
#define ZW (NCHMAX*NB*NKEY + NB*NSEM + NB*NN)   // 41,428 words

__device__ __forceinline__ unsigned u8x8_to_bits(uint2 v) {
  unsigned lo = (((v.x & 0x01010101u) * 0x01020408u) >> 24) & 0xFu;
  unsigned hi = (((v.y & 0x01010101u) * 0x01020408u) >> 24) & 0xFu;
  return lo | (hi << 4);
}

// ---------------- K0: zero ws stripe, owner=0xFF, detect, sort ----------------
__global__ __launch_bounds__(THR) void k0_setup(
    const void* __restrict__ masks, const float* __restrict__ scores,
    const int* __restrict__ cls, WS* __restrict__ ws, uint8_t* __restrict__ owner) {
  const int t = threadIdx.x, gid = blockIdx.x;
  unsigned tg = (unsigned)gid * THR + t;
  if (tg < (unsigned)ZW) (&ws->hist[0][0][0])[tg] = 0;
  uint4* ow = (uint4*)owner;
  const unsigned nw = (unsigned)(NB * HWP / 16);
  for (unsigned i = tg; i < nw; i += (unsigned)GRID * THR)
    ow[i] = make_uint4(~0u, ~0u, ~0u, ~0u);
  if (gid == 0) {
    __shared__ float ss[NB * NN];
    __shared__ unsigned shDet;
    const unsigned* mw = (const unsigned*)masks;
    unsigned any = 0;
    for (int i = t; i < 4096; i += THR) any |= (mw[i] > 1u) ? 1u : 0u;
    if (t == 0) shDet = 0;
    if (t < NB * NN) ss[t] = scores[t];
    if (t < NB) ws->Mcnt[t] = 0;
    __syncthreads();
    if (any) atomicOr(&shDet, 1u);
    __syncthreads();
    if (t == 0) ws->flag = shDet;
    if (t < NB * NN) {
      int bb = t / NN, i = t % NN;
      float s = ss[bb * NN + i];
      if (s >= 0.5f) {   // only candidates can ever be kept; others are no-ops
        int r = 0;
        for (int j = 0; j < NN; ++j) {
          float sj = ss[bb * NN + j];
          if (sj >= 0.5f && (sj > s || (sj == s && j < i))) r++;
        }
        ws->order[bb][r]   = i;
        ws->score_s[bb][r] = s;
        ws->cls_s[bb][r]   = cls[bb * NN + i];
        atomicAdd(&ws->Mcnt[bb], 1u);
      }
    }
  }
}

// ---- per-chunk: resolve(c-1) + apply(c-1) + hist(c)   [or tail: +counts] ----
__global__ __launch_bounds__(THR, 4) void k_chunk(
    const void* __restrict__ masks, const int* __restrict__ sem,
    WS* __restrict__ ws, uint8_t* __restrict__ owner, uint16_t* __restrict__ memb,
    int c, int doHist, int doCounts) {
  __shared__ unsigned lh[NKEY];
  __shared__ int midx[GCH];
  __shared__ unsigned sh_kmask;
  const int t = threadIdx.x, gid = blockIdx.x;
  const int b = gid / BPI, bx = gid % BPI;
  const int M = (int)ws->Mcnt[b];
  int Lp = (c > 0) ? (M - (c - 1) * GCH) : 0; if (Lp > GCH) Lp = GCH;
  int Lc = doHist ? (M - c * GCH) : 0;        if (Lc > GCH) Lc = GCH;
  if (!doCounts && Lp <= 0 && Lc <= 0) return;

  // resolve chunk c-1 redundantly per block (same inputs -> same result)
  unsigned kmask = 0;
  if (Lp > 0) {
    for (int i = t; i < NKEY; i += THR) lh[i] = ws->hist[c - 1][b][i];
    __syncthreads();
    if (t < 64) {
      unsigned km = 0;
      unsigned kc = (c >= 2) ? ws->kcAfter[c - 2][b] : 0u;
      for (int g = 0; g < Lp; ++g) {
        unsigned sel = km & ((1u << g) - 1u);
        unsigned area = 0, inter = 0;
        for (int i = t; i < NKEY; i += 64) {
          unsigned h = lh[i];
          if (h && (((unsigned)i >> g) & 1u)) {
            area += h;
            if (((unsigned)i >> GCH) | ((unsigned)i & sel)) inter += h;
          }
        }
        #pragma unroll
        for (int off = 32; off; off >>= 1) {
          area  += __shfl_xor(area, off);
          inter += __shfl_xor(inter, off);
        }
        float s = ws->score_s[b][(c - 1) * GCH + g];
        // inter <= 0.5f*area (exact in f32, area < 2^24)  <=>  2*inter <= area
        bool keep = (s >= 0.5f) && (area > 0u) && (2u * inter <= area);
        if (keep) {
          km |= 1u << g; kc += 1u;
          if (t == 0 && bx == 0) ws->iid[b][(c - 1) * GCH + g] = (int)kc;
        }
      }
      if (t == 0) { sh_kmask = km; if (bx == 0) ws->kcAfter[c - 1][b] = kc; }
    }
    __syncthreads();
    kmask = sh_kmask;
  }

  if (Lc > 0) {
    for (int i = t; i < NKEY; i += THR) lh[i] = 0;
    if (t < GCH) midx[t] = ws->order[b][(t < Lc) ? (c * GCH + t) : (c * GCH)];
  } else if (doCounts) {
    for (int i = t; i < NSEM; i += THR) lh[i] = 0;
  }
  __syncthreads();

  const int mode_u8 = (int)ws->flag;
  const size_t sbase = (size_t)b * HWP + (size_t)bx * PPB;
  const unsigned lm = (Lc >= GCH) ? (CBIT - 1u) : ((Lc > 0) ? ((1u << Lc) - 1u) : 0u);
  int midx_r[GCH];
  if (Lc > 0) {
    #pragma unroll
    for (int g = 0; g < GCH; ++g) midx_r[g] = __builtin_amdgcn_readfirstlane(midx[g]);
  }

  for (int s = 0; s < 2; ++s) {
    int gr = s * THR + t;
    if (gr >= NG) break;
    int l0 = gr * GPX;
    uint2 ov = *(const uint2*)(owner + sbase + l0);
    unsigned w2[2] = {ov.x, ov.y};
    if (kmask) {                       // apply chunk c-1 to this granule
      uint4 mo = *(const uint4*)(memb + sbase + l0);
      unsigned mw[4] = {mo.x, mo.y, mo.z, mo.w};
      bool chg = false;
      #pragma unroll
      for (int k = 0; k < GPX; ++k) {
        unsigned by = (w2[k >> 2] >> ((k & 3) * 8)) & 0xFFu;
        if (by == 0xFFu) {
          unsigned hit = (mw[k >> 1] >> ((k & 1) * 16)) & kmask;
          if (hit) {
            unsigned nb = (unsigned)((c - 1) * GCH + __builtin_ctz(hit));
            w2[k >> 2] = (w2[k >> 2] & ~(0xFFu << ((k & 3) * 8))) | (nb << ((k & 3) * 8));
            chg = true;
          }
        }
      }
      if (chg) *(uint2*)(owner + sbase + l0) = make_uint2(w2[0], w2[1]);
    }
    if (Lc > 0) {                      // hist for chunk c
      unsigned key[GPX];
      #pragma unroll
      for (int k = 0; k < GPX; ++k) {
        unsigned by = (w2[k >> 2] >> ((k & 3) * 8)) & 0xFFu;
        key[k] = (by != 0xFFu) ? CBIT : 0u;
      }
      if (mode_u8) {
        #pragma unroll
        for (int g = 0; g < GCH; ++g) {
          const uint8_t* mp = (const uint8_t*)masks +
              (size_t)(b * NN + midx_r[g]) * HWP + (size_t)bx * PPB + l0;
          unsigned b8 = u8x8_to_bits(*(const uint2*)mp);
          #pragma unroll
          for (int k = 0; k < GPX; ++k) key[k] |= ((b8 >> k) & 1u) << g;
        }
      } else {
        #pragma unroll 2
        for (int g = 0; g < GCH; ++g) {
          const uint4* mp = (const uint4*)((const int*)masks +
              (size_t)(b * NN + midx_r[g]) * HWP + (size_t)bx * PPB + l0);
          uint4 a = mp[0], bq = mp[1];
          unsigned b8 = (a.x & 1u) | ((a.y & 1u) << 1) | ((a.z & 1u) << 2) |
                        ((a.w & 1u) << 3) | ((bq.x & 1u) << 4) | ((bq.y & 1u) << 5) |
                        ((bq.z & 1u) << 6) | ((bq.w & 1u) << 7);
          #pragma unroll
          for (int k = 0; k < GPX; ++k) key[k] |= ((b8 >> k) & 1u) << g;
        }
      }
      unsigned fk[GPX];
      #pragma unroll
      for (int k = 0; k < GPX; ++k) fk[k] = key[k] & (lm | CBIT);
      uint4 pk;
      pk.x = fk[0] | (fk[1] << 16); pk.y = fk[2] | (fk[3] << 16);
      pk.z = fk[4] | (fk[5] << 16); pk.w = fk[6] | (fk[7] << 16);
      *(uint4*)(memb + sbase + l0) = pk;
      #pragma unroll
      for (int k = 0; k < GPX; ++k) atomicAdd(&lh[fk[k]], 1u);
    }
    if (doCounts) {                    // stuff areas over unclaimed pixels
      const uint4* sp = (const uint4*)(sem + sbase + l0);
      uint4 sv0 = sp[0], sv1 = sp[1];
      unsigned sarr[8] = {sv0.x, sv0.y, sv0.z, sv0.w, sv1.x, sv1.y, sv1.z, sv1.w};
      #pragma unroll
      for (int k = 0; k < GPX; ++k) {
        unsigned by = (w2[k >> 2] >> ((k & 3) * 8)) & 0xFFu;
        if (by == 0xFFu && sarr[k] != (unsigned)IGN) atomicAdd(&lh[sarr[k]], 1u);
      }
    }
  }
  __syncthreads();
  if (Lc > 0) {
    for (int i = t; i < NKEY; i += THR) {
      unsigned v = lh[i];
      if (v) atomicAdd(&ws->hist[c][b][i], v);
    }
  } else if (doCounts) {
    for (int i = t; i < NSEM; i += THR) {
      unsigned v = lh[i];
      if (v) atomicAdd(&ws->counts[b][i], v);
    }
  }
}

// ---------------- K3: final pan write ----------------
__global__ __launch_bounds__(THR) void k_writepan(
    const int* __restrict__ sem, const uint8_t* __restrict__ owner,
    const WS* __restrict__ ws, int* __restrict__ out) {
  __shared__ int pval[NN];
  __shared__ int sval[NSEM];
  const int t = threadIdx.x, gid = blockIdx.x;
  const int b = gid / BPI, bx = gid % BPI;
  const size_t sbase = (size_t)b * HWP + (size_t)bx * PPB;
  if (t < NN)  pval[t] = ws->cls_s[b][t] + ws->iid[b][t] * 1000;
  if (t < NSEM) sval[t] = (t != IGN && ws->counts[b][t] >= 4096u) ? (t + 80) : 0;
  __syncthreads();
  for (int s = 0; s < 2; ++s) {
    int gr = s * THR + t;
    if (gr >= NG) break;
    int l0 = gr * GPX;
    uint2 ov = *(const uint2*)(owner + sbase + l0);
    unsigned w2[2] = {ov.x, ov.y};
    const uint4* sp = (const uint4*)(sem + sbase + l0);
    uint4 sv0 = sp[0], sv1 = sp[1];
    unsigned sarr[8] = {sv0.x, sv0.y, sv0.z, sv0.w, sv1.x, sv1.y, sv1.z, sv1.w};
    int4* op = (int4*)(out + sbase + l0);
    #pragma unroll
    for (int q = 0; q < 2; ++q) {
      int res[4];
      #pragma unroll
      for (int j = 0; j < 4; ++j) {
        int k = q * 4 + j;
        unsigned by = (w2[k >> 2] >> ((k & 3) * 8)) & 0xFFu;
        res[j] = (by != 0xFFu) ? pval[by] : sval[sarr[k]];
      }
      op[q] = make_int4(res[0], res[1], res[2], res[3]);
    }
  }
}

extern "C" void kernel_launch(void* const* d_in, const int* in_sizes, int n_in,
                              void* d_out, int out_size, void* d_ws, size_t ws_size,
                              hipStream_t stream) {
  const void*  masks  = d_in[0];
  const float* scores = (const float*)d_in[1];
  const int*   cls    = (const int*)d_in[2];
  const int*   sem    = (const int*)d_in[3];
  int* out = (int*)d_out;

  uint8_t* base = (uint8_t*)d_ws;
  WS* ws = (WS*)base;
  size_t off = (sizeof(WS) + 255) & ~(size_t)255;
  uint8_t*  owner = base + off;
  size_t ob = ((size_t)NB * HWP + 255) & ~(size_t)255;
  uint16_t* memb  = (uint16_t*)(base + off + ob);

  hipLaunchKernelGGL(k0_setup, dim3(GRID), dim3(THR), 0, stream,
                     masks, scores, cls, ws, owner);
  for (int c = 0; c < NCHMAX; ++c)
    hipLaunchKernelGGL(k_chunk, dim3(GRID), dim3(THR), 0, stream,
                       masks, sem, ws, owner, memb, c, 1, 0);
  // tail: resolve+apply chunk NCHMAX-1 (if active) + stuff counts
  hipLaunchKernelGGL(k_chunk, dim3(GRID), dim3(THR), 0, stream,
                     masks, sem, ws, owner, memb, NCHMAX, 0, 1);
  hipLaunchKernelGGL(k_writepan, dim3(GRID), dim3(THR), 0, stream,
                     sem, owner, ws, out);
}